// Round 5
// baseline (427.871 us; speedup 1.0000x reference)
//
#include <hip/hip_runtime.h>
#include <math.h>

// ---------------------------------------------------------------------------
// GAU-alpha fused block for MI355X (gfx950).
// B=64, S=512, H=512, E=1024, UV=2176, D=128, M=B*S=32768.
// bf16 MFMA (16x16x32) all matmuls; fp32 elsewhere.
// Round 5: epilogue overhaul. mfma operand swap -> acc holds C^T (4 consecutive
// n per reg quad) -> packed ds_write_b64 LDS transpose -> fully coalesced b128
// global stores. gemm_out stores acc directly as fp32 b128 + coalesced x reads.
// ---------------------------------------------------------------------------

#define M_TOT   32768
#define S_LEN   512
#define H_DIM   512
#define E_DIMC  1024
#define UV_DIM  2176
#define D_DIM   128

using floatx4  = __attribute__((ext_vector_type(4))) float;
using uintx2   = __attribute__((ext_vector_type(2))) unsigned int;
using uintx4   = __attribute__((ext_vector_type(4))) unsigned int;
using ushortx4 = __attribute__((ext_vector_type(4))) unsigned short;
using short8   = __attribute__((ext_vector_type(8))) short;

#define ASYNC_CP16(gsrc, ldst)                                                  \
    __builtin_amdgcn_global_load_lds(                                           \
        (const __attribute__((address_space(1))) void*)(gsrc),                  \
        (__attribute__((address_space(3))) void*)(ldst), 16, 0, 0)

__device__ __forceinline__ float bf2f(unsigned short h) {
    union { unsigned int u; float f; } c;
    c.u = ((unsigned int)h) << 16;
    return c.f;
}
__device__ __forceinline__ unsigned short f2bf(float f) {
    union { float f; unsigned int u; } c;
    c.f = f;
    unsigned int r = c.u + 0x7fffu + ((c.u >> 16) & 1u);  // RNE
    return (unsigned short)(r >> 16);
}
__device__ __forceinline__ float silu_fast(float x) {
    float e = __expf(-x);                       // v_exp_f32
    return x * __builtin_amdgcn_rcpf(1.0f + e); // v_rcp_f32
}

// ---------------------------------------------------------------------------
__global__ __launch_bounds__(256) void f2bf_kernel(const float* __restrict__ in,
                                                   unsigned short* __restrict__ out,
                                                   int n4) {
    int i = blockIdx.x * 256 + threadIdx.x;
    if (i < n4) {
        floatx4 v = ((const floatx4*)in)[i];
        ushortx4 o;
        o.x = f2bf(v.x); o.y = f2bf(v.y); o.z = f2bf(v.z); o.w = f2bf(v.w);
        ((ushortx4*)out)[i] = o;
    }
}

// ---------------------------------------------------------------------------
__global__ __launch_bounds__(256) void rmsnorm_kernel(const float* __restrict__ x,
                                                      const float* __restrict__ ln_g,
                                                      unsigned short* __restrict__ xn) {
    int row  = blockIdx.x * 4 + (threadIdx.x >> 6);
    int lane = threadIdx.x & 63;
    const float* xr = x + (size_t)row * H_DIM;
    floatx4 v0 = ((const floatx4*)xr)[lane];
    floatx4 v1 = ((const floatx4*)xr)[lane + 64];
    float ss = v0.x*v0.x + v0.y*v0.y + v0.z*v0.z + v0.w*v0.w
             + v1.x*v1.x + v1.y*v1.y + v1.z*v1.z + v1.w*v1.w;
    #pragma unroll
    for (int off = 32; off > 0; off >>= 1) ss += __shfl_xor(ss, off, 64);
    float norm = sqrtf(ss) * 0.044194173824159216f;  // * H^-0.5
    float sc   = ln_g[0] / fmaxf(norm, 1e-5f);
    unsigned short* xo = xn + (size_t)row * H_DIM;
    ushortx4 o0, o1;
    o0.x = f2bf(v0.x * sc); o0.y = f2bf(v0.y * sc);
    o0.z = f2bf(v0.z * sc); o0.w = f2bf(v0.w * sc);
    o1.x = f2bf(v1.x * sc); o1.y = f2bf(v1.y * sc);
    o1.z = f2bf(v1.z * sc); o1.w = f2bf(v1.w * sc);
    ((ushortx4*)xo)[lane]      = o0;
    ((ushortx4*)xo)[lane + 64] = o1;
}

// ---------------------------------------------------------------------------
__global__ __launch_bounds__(64) void rope_table_kernel(float* __restrict__ cost,
                                                        float* __restrict__ sint) {
    int s = blockIdx.x;
    int j = threadIdx.x;  // 0..63
    float invf = (float)pow(10000.0, (double)j / 64.0);
    float ang  = (float)s * invf;  // fp32 multiply like the f32 reference
    double a   = (double)ang;
    cost[s * 64 + j] = (float)cos(a);
    sint[s * 64 + j] = (float)sin(a);
}

// ---------------------------------------------------------------------------
__global__ __launch_bounds__(256) void rope_apply_kernel(const float* __restrict__ base,
                                                         const float* __restrict__ gamma,
                                                         const float* __restrict__ beta,
                                                         const float* __restrict__ cost,
                                                         const float* __restrict__ sint,
                                                         unsigned short* __restrict__ q,
                                                         unsigned short* __restrict__ k) {
    int idx = blockIdx.x * 256 + threadIdx.x;  // M*64 total
    int m = idx >> 6;
    int j = idx & 63;
    int s = m & (S_LEN - 1);
    float b1 = base[(size_t)m * D_DIM + j];
    float b2 = base[(size_t)m * D_DIM + 64 + j];
    float c  = cost[s * 64 + j];
    float sn = sint[s * 64 + j];
    float yq1 = b1 * gamma[j]       + beta[j];
    float yq2 = b2 * gamma[64 + j]  + beta[64 + j];
    float yk1 = b1 * gamma[128 + j] + beta[128 + j];
    float yk2 = b2 * gamma[192 + j] + beta[192 + j];
    q[(size_t)m * D_DIM + j]      = f2bf(yq1 * c - yq2 * sn);
    q[(size_t)m * D_DIM + 64 + j] = f2bf(yq2 * c + yq1 * sn);
    k[(size_t)m * D_DIM + j]      = f2bf(yk1 * c - yk2 * sn);
    k[(size_t)m * D_DIM + 64 + j] = f2bf(yk2 * c + yk1 * sn);
}

// ---------------------------------------------------------------------------
// GEMM core, B^T form: C[m][n] = sum_k A[m][k]*B[n][k].
// 128x128 tile, 4 waves (64x64 each), 16x16x32 bf16 MFMA, BK=64.
// Staging: global_load_lds w=16, XOR-swizzled: LDS[r][c] = G[r][c ^ 8*(r&7)].
// SWAPT=false: acc[mt][nt] C-layout: m = wm+mt*16+quad*4+r, n = wn+nt*16+l16
// SWAPT=true : operands swapped -> C^T:  m = wm+mt*16+l16, n = wn+nt*16+quad*4+r
// ---------------------------------------------------------------------------
struct GemmLds {
    unsigned short As[128 * 64];
    unsigned short Bs[128 * 64];
};

template <bool SWAPT>
__device__ __forceinline__ void gemm_bt_core(const unsigned short* __restrict__ A,
                                             const unsigned short* __restrict__ B,
                                             int lda, int ldb, int K,
                                             int m0, int n0,
                                             GemmLds& lds, floatx4 (&acc)[4][4]) {
    const int tid  = threadIdx.x;
    const int lane = tid & 63;
    const int wave = tid >> 6;
    const int quad = lane >> 4;
    const int l16  = lane & 15;
    const int wm   = (wave >> 1) * 64;
    const int wn   = (wave & 1) * 64;
    const int lrow = lane >> 3;                    // 0..7
    const int cgs  = ((lane & 7) ^ lrow) * 8;      // swizzled source col (shorts)

    #pragma unroll
    for (int i = 0; i < 4; i++)
        #pragma unroll
        for (int j = 0; j < 4; j++) acc[i][j] = (floatx4){0.f, 0.f, 0.f, 0.f};

    for (int kt = 0; kt < K; kt += 64) {
        #pragma unroll
        for (int i = 0; i < 4; i++) {
            int r0 = wave * 32 + i * 8;
            const unsigned short* ga = A + (size_t)(m0 + r0 + lrow) * lda + kt + cgs;
            const unsigned short* gb = B + (size_t)(n0 + r0 + lrow) * ldb + kt + cgs;
            ASYNC_CP16(ga, &lds.As[r0 * 64]);
            ASYNC_CP16(gb, &lds.Bs[r0 * 64]);
        }
        __syncthreads();
        #pragma unroll
        for (int kk = 0; kk < 64; kk += 32) {
            short8 af[4], bf[4];
            const int pc = (kk + quad * 8) ^ ((l16 & 7) * 8);  // physical col
            #pragma unroll
            for (int mt = 0; mt < 4; mt++) {
                int row = wm + mt * 16 + l16;
                union { short8 s8; uintx4 u4; } fu;
                fu.u4 = *(const uintx4*)&lds.As[row * 64 + pc];
                af[mt] = fu.s8;
            }
            #pragma unroll
            for (int nt = 0; nt < 4; nt++) {
                int row = wn + nt * 16 + l16;
                union { short8 s8; uintx4 u4; } fu;
                fu.u4 = *(const uintx4*)&lds.Bs[row * 64 + pc];
                bf[nt] = fu.s8;
            }
            #pragma unroll
            for (int mt = 0; mt < 4; mt++)
                #pragma unroll
                for (int nt = 0; nt < 4; nt++)
                    acc[mt][nt] = SWAPT
                        ? __builtin_amdgcn_mfma_f32_16x16x32_bf16(bf[nt], af[mt], acc[mt][nt], 0, 0, 0)
                        : __builtin_amdgcn_mfma_f32_16x16x32_bf16(af[mt], bf[nt], acc[mt][nt], 0, 0, 0);
        }
        __syncthreads();
    }
}

// shared LDS union for bf16-tile epilogues
union LdsU {
    GemmLds g;
    unsigned short T[128 * 136];   // 34816 B, pitch 136
};

// ---------------------------------------------------------------------------
// GEMM1-u: u columns (n0 = by*128), SWAPPED acc; silu; LDS transpose; b128 out
// ---------------------------------------------------------------------------
__global__ __launch_bounds__(256) void gemm1_u_kernel(const unsigned short* __restrict__ xn,
                                                      const unsigned short* __restrict__ uvw,
                                                      const float* __restrict__ uvb,
                                                      unsigned short* __restrict__ u) {
    __shared__ LdsU lds;
    floatx4 acc[4][4];
    const int m0 = blockIdx.x * 128, n0 = blockIdx.y * 128;
    gemm_bt_core<true>(xn, uvw, H_DIM, H_DIM, H_DIM, m0, n0, lds.g, acc);

    const int tid = threadIdx.x, lane = tid & 63, wave = tid >> 6;
    const int quad = lane >> 4, l16 = lane & 15;
    const int wm = (wave >> 1) * 64, wn = (wave & 1) * 64;

    #pragma unroll
    for (int mt = 0; mt < 4; mt++)
        #pragma unroll
        for (int nt = 0; nt < 4; nt++) {
            int nl = wn + nt * 16 + quad * 4;
            floatx4 b4 = *(const floatx4*)&uvb[n0 + nl];
            ushortx4 pk;
            #pragma unroll
            for (int r = 0; r < 4; r++)
                pk[r] = f2bf(silu_fast(acc[mt][nt][r] + b4[r]));
            *(uintx2*)&lds.T[(wm + mt * 16 + l16) * 136 + nl] = *(uintx2*)&pk;
        }
    __syncthreads();
    #pragma unroll
    for (int i = 0; i < 8; i++) {
        int idx = tid + i * 256;       // 0..2047
        int row = idx >> 4;            // 0..127
        int c8  = (idx & 15) * 8;      // 0..120
        *(uintx4*)(u + (size_t)(m0 + row) * E_DIMC + n0 + c8) =
            *(const uintx4*)&lds.T[row * 136 + c8];
    }
}

// ---------------------------------------------------------------------------
// GEMM1-v/base: by<8 -> v columns (n0=1024+by*128), UNSWAPPED, transpose to vT;
//               by==8 -> base columns (n0=2048), fp32 scalar stores.
// ---------------------------------------------------------------------------
__global__ __launch_bounds__(256) void gemm1_vbase_kernel(const unsigned short* __restrict__ xn,
                                                          const unsigned short* __restrict__ uvw,
                                                          const float* __restrict__ uvb,
                                                          unsigned short* __restrict__ vT,
                                                          float* __restrict__ base) {
    __shared__ LdsU lds;
    floatx4 acc[4][4];
    const int m0 = blockIdx.x * 128;
    const int n0 = E_DIMC + blockIdx.y * 128;  // 1024..2176
    gemm_bt_core<false>(xn, uvw, H_DIM, H_DIM, H_DIM, m0, n0, lds.g, acc);

    const int tid = threadIdx.x, lane = tid & 63, wave = tid >> 6;
    const int quad = lane >> 4, l16 = lane & 15;
    const int wm = (wave >> 1) * 64, wn = (wave & 1) * 64;

    if (blockIdx.y < 8) {
        // v: pack along m (quad*4+r), tile layout T[n][m], then store vT (b,e,s)
        #pragma unroll
        for (int nt = 0; nt < 4; nt++) {
            int nl = wn + nt * 16 + l16;
            float bias = uvb[n0 + nl];
            #pragma unroll
            for (int mt = 0; mt < 4; mt++) {
                ushortx4 pk;
                #pragma unroll
                for (int r = 0; r < 4; r++)
                    pk[r] = f2bf(silu_fast(acc[mt][nt][r] + bias));
                *(uintx2*)&lds.T[nl * 136 + wm + mt * 16 + quad * 4] = *(uintx2*)&pk;
            }
        }
        __syncthreads();
        const int b   = m0 >> 9;
        const int sg0 = m0 & (S_LEN - 1);
        const int eg0 = n0 - E_DIMC;
        #pragma unroll
        for (int i = 0; i < 8; i++) {
            int idx = tid + i * 256;
            int e   = idx >> 4;
            int s8  = (idx & 15) * 8;
            *(uintx4*)(vT + ((size_t)b * E_DIMC + eg0 + e) * S_LEN + sg0 + s8) =
                *(const uintx4*)&lds.T[e * 136 + s8];
        }
    } else {
        #pragma unroll
        for (int mt = 0; mt < 4; mt++)
            #pragma unroll
            for (int nt = 0; nt < 4; nt++)
                #pragma unroll
                for (int r = 0; r < 4; r++) {
                    int m = m0 + wm + mt * 16 + quad * 4 + r;
                    int n = n0 + wn + nt * 16 + l16;
                    float val = acc[mt][nt][r] + uvb[n];
                    base[(size_t)m * D_DIM + (n - 2 * E_DIMC)] = silu_fast(val);
                }
    }
}

// ---------------------------------------------------------------------------
// qk: P = relu((q k^T + w_bias)/sqrt(128))^2, SWAPPED, LDS transpose, b128 out
// ---------------------------------------------------------------------------
__global__ __launch_bounds__(256) void gemm_qk_kernel(const unsigned short* __restrict__ q,
                                                      const unsigned short* __restrict__ k,
                                                      const float* __restrict__ wbias,
                                                      unsigned short* __restrict__ P) {
    __shared__ LdsU lds;
    floatx4 acc[4][4];
    size_t boff = (size_t)blockIdx.z * S_LEN * D_DIM;
    unsigned short* Pb = P + (size_t)blockIdx.z * S_LEN * S_LEN;
    const int m0 = blockIdx.x * 128, n0 = blockIdx.y * 128;
    gemm_bt_core<true>(q + boff, k + boff, D_DIM, D_DIM, D_DIM, m0, n0, lds.g, acc);

    const int tid = threadIdx.x, lane = tid & 63, wave = tid >> 6;
    const int quad = lane >> 4, l16 = lane & 15;
    const int wm = (wave >> 1) * 64, wn = (wave & 1) * 64;
    #pragma unroll
    for (int mt = 0; mt < 4; mt++) {
        int s = m0 + wm + mt * 16 + l16;
        #pragma unroll
        for (int nt = 0; nt < 4; nt++) {
            int nl = wn + nt * 16 + quad * 4;
            int t0 = n0 + nl;
            ushortx4 pk;
            #pragma unroll
            for (int r = 0; r < 4; r++) {
                float z = (acc[mt][nt][r] + wbias[t0 + r - s + (S_LEN - 1)]) * 0.08838834764831845f;
                z = fmaxf(z, 0.f);
                pk[r] = f2bf(z * z);
            }
            *(uintx2*)&lds.T[(wm + mt * 16 + l16) * 136 + nl] = *(uintx2*)&pk;
        }
    }
    __syncthreads();
    #pragma unroll
    for (int i = 0; i < 8; i++) {
        int idx = tid + i * 256;
        int row = idx >> 4;
        int c8  = (idx & 15) * 8;
        *(uintx4*)(Pb + (size_t)(m0 + row) * S_LEN + n0 + c8) =
            *(const uintx4*)&lds.T[row * 136 + c8];
    }
}

// ---------------------------------------------------------------------------
// PV: u <- u .* (P @ v), SWAPPED, LDS transpose, coalesced in-place update
// ---------------------------------------------------------------------------
__global__ __launch_bounds__(256) void gemm_pv_kernel(const unsigned short* __restrict__ P,
                                                      const unsigned short* __restrict__ vT,
                                                      unsigned short* __restrict__ u) {
    __shared__ LdsU lds;
    floatx4 acc[4][4];
    int bb = blockIdx.z;
    const unsigned short* Pb  = P  + (size_t)bb * S_LEN * S_LEN;
    const unsigned short* vTb = vT + (size_t)bb * E_DIMC * S_LEN;
    const int m0 = blockIdx.x * 128, n0 = blockIdx.y * 128;
    gemm_bt_core<true>(Pb, vTb, S_LEN, S_LEN, S_LEN, m0, n0, lds.g, acc);

    const int tid = threadIdx.x, lane = tid & 63, wave = tid >> 6;
    const int quad = lane >> 4, l16 = lane & 15;
    const int wm = (wave >> 1) * 64, wn = (wave & 1) * 64;
    #pragma unroll
    for (int mt = 0; mt < 4; mt++)
        #pragma unroll
        for (int nt = 0; nt < 4; nt++) {
            int nl = wn + nt * 16 + quad * 4;
            ushortx4 pk;
            #pragma unroll
            for (int r = 0; r < 4; r++) pk[r] = f2bf(acc[mt][nt][r]);
            *(uintx2*)&lds.T[(wm + mt * 16 + l16) * 136 + nl] = *(uintx2*)&pk;
        }
    __syncthreads();
    #pragma unroll
    for (int i = 0; i < 8; i++) {
        int idx = tid + i * 256;
        int row = idx >> 4;
        int c8  = (idx & 15) * 8;
        size_t off = ((size_t)bb * S_LEN + m0 + row) * E_DIMC + n0 + c8;
        union { uintx4 u4; unsigned short s[8]; } tv, uv, ov;
        tv.u4 = *(const uintx4*)&lds.T[row * 136 + c8];
        uv.u4 = *(const uintx4*)(u + off);
        #pragma unroll
        for (int j = 0; j < 8; j++) ov.s[j] = f2bf(bf2f(tv.s[j]) * bf2f(uv.s[j]));
        *(uintx4*)(u + off) = ov.u4;
    }
}

// ---------------------------------------------------------------------------
// OUT: out = oe @ o_w^T + o_b + x, SWAPPED. acc floatx4 = 4 consecutive n ->
// direct b128 into fp32 half-tiles; coalesced float4 x/o_b reads and stores.
// ---------------------------------------------------------------------------
__global__ __launch_bounds__(256) void gemm_out_kernel(const unsigned short* __restrict__ oe,
                                                       const unsigned short* __restrict__ ow,
                                                       const float* __restrict__ ob,
                                                       const float* __restrict__ x,
                                                       float* __restrict__ out) {
    __shared__ union {
        GemmLds g;
        float Tf[128 * 68];   // 34816 B, pitch 68 (64 cols + pad)
    } lds;
    floatx4 acc[4][4];
    const int m0 = blockIdx.x * 128, n0 = blockIdx.y * 128;
    gemm_bt_core<true>(oe, ow, E_DIMC, E_DIMC, E_DIMC, m0, n0, lds.g, acc);

    const int tid = threadIdx.x, lane = tid & 63, wave = tid >> 6;
    const int quad = lane >> 4, l16 = lane & 15;
    const int wm = (wave >> 1) * 64;

    #pragma unroll
    for (int h = 0; h < 2; h++) {
        if ((wave & 1) == h) {
            #pragma unroll
            for (int mt = 0; mt < 4; mt++)
                #pragma unroll
                for (int nt = 0; nt < 4; nt++)
                    *(floatx4*)&lds.Tf[(wm + mt * 16 + l16) * 68 + nt * 16 + quad * 4] =
                        acc[mt][nt];
        }
        __syncthreads();
        #pragma unroll
        for (int i = 0; i < 8; i++) {
            int idx = tid + i * 256;       // 0..2047
            int row = idx >> 4;            // 0..127
            int c4  = (idx & 15) * 4;      // 0..60
            int n   = n0 + h * 64 + c4;
            floatx4 val = *(const floatx4*)&lds.Tf[row * 68 + c4];
            floatx4 b4  = *(const floatx4*)&ob[n];
            floatx4 x4  = *(const floatx4*)&x[(size_t)(m0 + row) * H_DIM + n];
            val = val + b4 + x4;
            *(floatx4*)&out[(size_t)(m0 + row) * H_DIM + n] = val;
        }
        __syncthreads();
    }
}

// ---------------------------------------------------------------------------
extern "C" void kernel_launch(void* const* d_in, const int* in_sizes, int n_in,
                              void* d_out, int out_size, void* d_ws, size_t ws_size,
                              hipStream_t stream) {
    const float* x     = (const float*)d_in[0];
    const float* ln_g  = (const float*)d_in[1];
    const float* uv_w  = (const float*)d_in[2];
    const float* uv_b  = (const float*)d_in[3];
    const float* gamma = (const float*)d_in[4];
    const float* beta  = (const float*)d_in[5];
    const float* wbias = (const float*)d_in[6];
    const float* o_w   = (const float*)d_in[7];
    const float* o_b   = (const float*)d_in[8];
    float* out = (float*)d_out;

    char* ws = (char*)d_ws;
    size_t off = 0;
    auto alloc = [&](size_t bytes) {
        void* p = ws + off;
        off += (bytes + 255) & ~(size_t)255;
        return p;
    };
    // Peak ~196.4 MiB:
    unsigned short* u     = (unsigned short*)alloc((size_t)M_TOT * E_DIMC * 2);      // 64 MiB (u, then oe in place)
    unsigned short* vT    = (unsigned short*)alloc((size_t)64 * E_DIMC * S_LEN * 2); // 64 MiB
    unsigned short* xn    = (unsigned short*)alloc((size_t)M_TOT * H_DIM * 2);       // 32 MiB
    unsigned short* P     = xn;                                                      // alias (xn dead after gemm1)
    float*          base  = (float*)alloc((size_t)M_TOT * D_DIM * 4);                // 16 MiB
    unsigned short* q     = (unsigned short*)alloc((size_t)M_TOT * D_DIM * 2);       // 8 MiB
    unsigned short* k     = (unsigned short*)alloc((size_t)M_TOT * D_DIM * 2);       // 8 MiB
    float*          cost  = (float*)alloc((size_t)S_LEN * 64 * 4);
    float*          sint  = (float*)alloc((size_t)S_LEN * 64 * 4);
    unsigned short* uvwb  = (unsigned short*)alloc((size_t)UV_DIM * H_DIM * 2);      // 2.2 MiB
    unsigned short* owb   = (unsigned short*)alloc((size_t)H_DIM * E_DIMC * 2);      // 1 MiB
    (void)ws_size; (void)in_sizes; (void)n_in; (void)out_size;

    f2bf_kernel<<<(UV_DIM * H_DIM / 4 + 255) / 256, 256, 0, stream>>>(uv_w, uvwb, UV_DIM * H_DIM / 4);
    f2bf_kernel<<<(H_DIM * E_DIMC / 4 + 255) / 256, 256, 0, stream>>>(o_w, owb, H_DIM * E_DIMC / 4);
    rope_table_kernel<<<S_LEN, 64, 0, stream>>>(cost, sint);

    rmsnorm_kernel<<<M_TOT / 4, 256, 0, stream>>>(x, ln_g, xn);

    // gemm1 + silu: u (swapped) and v/base (unswapped)
    gemm1_u_kernel<<<dim3(M_TOT / 128, 8), 256, 0, stream>>>(xn, uvwb, uv_b, u);
    gemm1_vbase_kernel<<<dim3(M_TOT / 128, 9), 256, 0, stream>>>(xn, uvwb, uv_b, vT, base);

    rope_apply_kernel<<<M_TOT * 64 / 256, 256, 0, stream>>>(base, gamma, beta, cost, sint, q, k);

    // P = relu^2((q k^T + bias)/sqrt(128))   (overwrites xn region)
    gemm_qk_kernel<<<dim3(S_LEN / 128, S_LEN / 128, 64), 256, 0, stream>>>(q, k, wbias, P);

    // u <- u .* (P @ v)  in place
    gemm_pv_kernel<<<dim3(S_LEN / 128, E_DIMC / 128, 64), 256, 0, stream>>>(P, vT, u);

    // out = oe @ o_w^T + o_b + x
    gemm_out_kernel<<<dim3(M_TOT / 128, H_DIM / 128), 256, 0, stream>>>(u, owb, o_b, x, out);
}

// Round 6
// 409.642 us; speedup vs baseline: 1.0445x; 1.0445x over previous
//
#include <hip/hip_runtime.h>
#include <math.h>

// ---------------------------------------------------------------------------
// GAU-alpha fused block for MI355X (gfx950).
// B=64, S=512, H=512, E=1024, UV=2176, D=128, M=B*S=32768.
// bf16 MFMA (16x16x32) all matmuls; fp32 elsewhere.
// Round 6: fix round-5 epilogue LDS conflicts.
//  - gemm_out: NO LDS epilogue; swapped acc stored directly as float4 b128.
//  - bf16 tiles: pitch 128 + 16B-granular XOR swizzle (pair ^ (row&7)):
//    b64 writes 2-way (free), b128 reads conflict-free.
// ---------------------------------------------------------------------------

#define M_TOT   32768
#define S_LEN   512
#define H_DIM   512
#define E_DIMC  1024
#define UV_DIM  2176
#define D_DIM   128

using floatx4  = __attribute__((ext_vector_type(4))) float;
using uintx2   = __attribute__((ext_vector_type(2))) unsigned int;
using uintx4   = __attribute__((ext_vector_type(4))) unsigned int;
using ushortx4 = __attribute__((ext_vector_type(4))) unsigned short;
using short8   = __attribute__((ext_vector_type(8))) short;

#define ASYNC_CP16(gsrc, ldst)                                                  \
    __builtin_amdgcn_global_load_lds(                                           \
        (const __attribute__((address_space(1))) void*)(gsrc),                  \
        (__attribute__((address_space(3))) void*)(ldst), 16, 0, 0)

__device__ __forceinline__ float bf2f(unsigned short h) {
    union { unsigned int u; float f; } c;
    c.u = ((unsigned int)h) << 16;
    return c.f;
}
__device__ __forceinline__ unsigned short f2bf(float f) {
    union { float f; unsigned int u; } c;
    c.f = f;
    unsigned int r = c.u + 0x7fffu + ((c.u >> 16) & 1u);  // RNE
    return (unsigned short)(r >> 16);
}
__device__ __forceinline__ float silu_fast(float x) {
    float e = __expf(-x);                       // v_exp_f32
    return x * __builtin_amdgcn_rcpf(1.0f + e); // v_rcp_f32
}

// ---------------------------------------------------------------------------
__global__ __launch_bounds__(256) void f2bf_kernel(const float* __restrict__ in,
                                                   unsigned short* __restrict__ out,
                                                   int n4) {
    int i = blockIdx.x * 256 + threadIdx.x;
    if (i < n4) {
        floatx4 v = ((const floatx4*)in)[i];
        ushortx4 o;
        o.x = f2bf(v.x); o.y = f2bf(v.y); o.z = f2bf(v.z); o.w = f2bf(v.w);
        ((ushortx4*)out)[i] = o;
    }
}

// ---------------------------------------------------------------------------
__global__ __launch_bounds__(256) void rmsnorm_kernel(const float* __restrict__ x,
                                                      const float* __restrict__ ln_g,
                                                      unsigned short* __restrict__ xn) {
    int row  = blockIdx.x * 4 + (threadIdx.x >> 6);
    int lane = threadIdx.x & 63;
    const float* xr = x + (size_t)row * H_DIM;
    floatx4 v0 = ((const floatx4*)xr)[lane];
    floatx4 v1 = ((const floatx4*)xr)[lane + 64];
    float ss = v0.x*v0.x + v0.y*v0.y + v0.z*v0.z + v0.w*v0.w
             + v1.x*v1.x + v1.y*v1.y + v1.z*v1.z + v1.w*v1.w;
    #pragma unroll
    for (int off = 32; off > 0; off >>= 1) ss += __shfl_xor(ss, off, 64);
    float norm = sqrtf(ss) * 0.044194173824159216f;  // * H^-0.5
    float sc   = ln_g[0] / fmaxf(norm, 1e-5f);
    unsigned short* xo = xn + (size_t)row * H_DIM;
    ushortx4 o0, o1;
    o0.x = f2bf(v0.x * sc); o0.y = f2bf(v0.y * sc);
    o0.z = f2bf(v0.z * sc); o0.w = f2bf(v0.w * sc);
    o1.x = f2bf(v1.x * sc); o1.y = f2bf(v1.y * sc);
    o1.z = f2bf(v1.z * sc); o1.w = f2bf(v1.w * sc);
    ((ushortx4*)xo)[lane]      = o0;
    ((ushortx4*)xo)[lane + 64] = o1;
}

// ---------------------------------------------------------------------------
__global__ __launch_bounds__(64) void rope_table_kernel(float* __restrict__ cost,
                                                        float* __restrict__ sint) {
    int s = blockIdx.x;
    int j = threadIdx.x;  // 0..63
    float invf = (float)pow(10000.0, (double)j / 64.0);
    float ang  = (float)s * invf;  // fp32 multiply like the f32 reference
    double a   = (double)ang;
    cost[s * 64 + j] = (float)cos(a);
    sint[s * 64 + j] = (float)sin(a);
}

// ---------------------------------------------------------------------------
__global__ __launch_bounds__(256) void rope_apply_kernel(const float* __restrict__ base,
                                                         const float* __restrict__ gamma,
                                                         const float* __restrict__ beta,
                                                         const float* __restrict__ cost,
                                                         const float* __restrict__ sint,
                                                         unsigned short* __restrict__ q,
                                                         unsigned short* __restrict__ k) {
    int idx = blockIdx.x * 256 + threadIdx.x;  // M*64 total
    int m = idx >> 6;
    int j = idx & 63;
    int s = m & (S_LEN - 1);
    float b1 = base[(size_t)m * D_DIM + j];
    float b2 = base[(size_t)m * D_DIM + 64 + j];
    float c  = cost[s * 64 + j];
    float sn = sint[s * 64 + j];
    float yq1 = b1 * gamma[j]       + beta[j];
    float yq2 = b2 * gamma[64 + j]  + beta[64 + j];
    float yk1 = b1 * gamma[128 + j] + beta[128 + j];
    float yk2 = b2 * gamma[192 + j] + beta[192 + j];
    q[(size_t)m * D_DIM + j]      = f2bf(yq1 * c - yq2 * sn);
    q[(size_t)m * D_DIM + 64 + j] = f2bf(yq2 * c + yq1 * sn);
    k[(size_t)m * D_DIM + j]      = f2bf(yk1 * c - yk2 * sn);
    k[(size_t)m * D_DIM + 64 + j] = f2bf(yk2 * c + yk1 * sn);
}

// ---------------------------------------------------------------------------
// GEMM core, B^T form: C[m][n] = sum_k A[m][k]*B[n][k].
// 128x128 tile, 4 waves (64x64 each), 16x16x32 bf16 MFMA, BK=64.
// Staging: global_load_lds w=16, XOR-swizzled: LDS[r][c] = G[r][c ^ 8*(r&7)].
// SWAPT=false: acc C-layout: m = wm+mt*16+quad*4+r, n = wn+nt*16+l16
// SWAPT=true : C^T:           m = wm+mt*16+l16,     n = wn+nt*16+quad*4+r
// ---------------------------------------------------------------------------
struct GemmLds {
    unsigned short As[128 * 64];
    unsigned short Bs[128 * 64];
};

template <bool SWAPT>
__device__ __forceinline__ void gemm_bt_core(const unsigned short* __restrict__ A,
                                             const unsigned short* __restrict__ B,
                                             int lda, int ldb, int K,
                                             int m0, int n0,
                                             GemmLds& lds, floatx4 (&acc)[4][4]) {
    const int tid  = threadIdx.x;
    const int lane = tid & 63;
    const int wave = tid >> 6;
    const int quad = lane >> 4;
    const int l16  = lane & 15;
    const int wm   = (wave >> 1) * 64;
    const int wn   = (wave & 1) * 64;
    const int lrow = lane >> 3;                    // 0..7
    const int cgs  = ((lane & 7) ^ lrow) * 8;      // swizzled source col (shorts)

    #pragma unroll
    for (int i = 0; i < 4; i++)
        #pragma unroll
        for (int j = 0; j < 4; j++) acc[i][j] = (floatx4){0.f, 0.f, 0.f, 0.f};

    for (int kt = 0; kt < K; kt += 64) {
        #pragma unroll
        for (int i = 0; i < 4; i++) {
            int r0 = wave * 32 + i * 8;
            const unsigned short* ga = A + (size_t)(m0 + r0 + lrow) * lda + kt + cgs;
            const unsigned short* gb = B + (size_t)(n0 + r0 + lrow) * ldb + kt + cgs;
            ASYNC_CP16(ga, &lds.As[r0 * 64]);
            ASYNC_CP16(gb, &lds.Bs[r0 * 64]);
        }
        __syncthreads();
        #pragma unroll
        for (int kk = 0; kk < 64; kk += 32) {
            short8 af[4], bf[4];
            const int pc = (kk + quad * 8) ^ ((l16 & 7) * 8);  // physical col
            #pragma unroll
            for (int mt = 0; mt < 4; mt++) {
                int row = wm + mt * 16 + l16;
                union { short8 s8; uintx4 u4; } fu;
                fu.u4 = *(const uintx4*)&lds.As[row * 64 + pc];
                af[mt] = fu.s8;
            }
            #pragma unroll
            for (int nt = 0; nt < 4; nt++) {
                int row = wn + nt * 16 + l16;
                union { short8 s8; uintx4 u4; } fu;
                fu.u4 = *(const uintx4*)&lds.Bs[row * 64 + pc];
                bf[nt] = fu.s8;
            }
            #pragma unroll
            for (int mt = 0; mt < 4; mt++)
                #pragma unroll
                for (int nt = 0; nt < 4; nt++)
                    acc[mt][nt] = SWAPT
                        ? __builtin_amdgcn_mfma_f32_16x16x32_bf16(bf[nt], af[mt], acc[mt][nt], 0, 0, 0)
                        : __builtin_amdgcn_mfma_f32_16x16x32_bf16(af[mt], bf[nt], acc[mt][nt], 0, 0, 0);
        }
        __syncthreads();
    }
}

// bf16 epilogue tile: pitch 128 shorts, 16B-granular XOR swizzle:
//   phys 8B-chunk address: col -> ((col>>3) ^ (row&7))*8 + (col&7)
// Writes (b64, 2-way = free), reads (b128, conflict-free).
union LdsU {
    GemmLds g;
    unsigned short T[128 * 128];   // 32768 B == sizeof(GemmLds)
};
__device__ __forceinline__ int swz(int row, int col) {
    return row * 128 + ((((col >> 3) ^ (row & 7)) << 3) | (col & 7));
}

// ---------------------------------------------------------------------------
// GEMM1-u: u columns (n0 = by*128), SWAPPED acc; silu; swizzled LDS transpose
// ---------------------------------------------------------------------------
__global__ __launch_bounds__(256) void gemm1_u_kernel(const unsigned short* __restrict__ xn,
                                                      const unsigned short* __restrict__ uvw,
                                                      const float* __restrict__ uvb,
                                                      unsigned short* __restrict__ u) {
    __shared__ LdsU lds;
    floatx4 acc[4][4];
    const int m0 = blockIdx.x * 128, n0 = blockIdx.y * 128;
    gemm_bt_core<true>(xn, uvw, H_DIM, H_DIM, H_DIM, m0, n0, lds.g, acc);

    const int tid = threadIdx.x, lane = tid & 63, wave = tid >> 6;
    const int quad = lane >> 4, l16 = lane & 15;
    const int wm = (wave >> 1) * 64, wn = (wave & 1) * 64;

    #pragma unroll
    for (int mt = 0; mt < 4; mt++) {
        int row = wm + mt * 16 + l16;
        #pragma unroll
        for (int nt = 0; nt < 4; nt++) {
            int nl = wn + nt * 16 + quad * 4;
            floatx4 b4 = *(const floatx4*)&uvb[n0 + nl];
            ushortx4 pk;
            #pragma unroll
            for (int r = 0; r < 4; r++)
                pk[r] = f2bf(silu_fast(acc[mt][nt][r] + b4[r]));
            *(uintx2*)&lds.T[swz(row, nl)] = *(uintx2*)&pk;
        }
    }
    __syncthreads();
    #pragma unroll
    for (int i = 0; i < 8; i++) {
        int idx = tid + i * 256;       // 0..2047
        int row = idx >> 4;            // 0..127
        int j   = idx & 15;
        *(uintx4*)(u + (size_t)(m0 + row) * E_DIMC + n0 + j * 8) =
            *(const uintx4*)&lds.T[swz(row, j * 8)];
    }
}

// ---------------------------------------------------------------------------
// GEMM1-v/base: by<8 -> v (n0=1024+by*128), UNSWAPPED, transpose to vT;
//               by==8 -> base (n0=2048), fp32 scalar stores.
// ---------------------------------------------------------------------------
__global__ __launch_bounds__(256) void gemm1_vbase_kernel(const unsigned short* __restrict__ xn,
                                                          const unsigned short* __restrict__ uvw,
                                                          const float* __restrict__ uvb,
                                                          unsigned short* __restrict__ vT,
                                                          float* __restrict__ base) {
    __shared__ LdsU lds;
    floatx4 acc[4][4];
    const int m0 = blockIdx.x * 128;
    const int n0 = E_DIMC + blockIdx.y * 128;  // 1024..2176
    gemm_bt_core<false>(xn, uvw, H_DIM, H_DIM, H_DIM, m0, n0, lds.g, acc);

    const int tid = threadIdx.x, lane = tid & 63, wave = tid >> 6;
    const int quad = lane >> 4, l16 = lane & 15;
    const int wm = (wave >> 1) * 64, wn = (wave & 1) * 64;

    if (blockIdx.y < 8) {
        // v: T[n][m] (pack along m = quad*4+r), swizzled; then store vT (b,e,s)
        #pragma unroll
        for (int nt = 0; nt < 4; nt++) {
            int nl = wn + nt * 16 + l16;
            float bias = uvb[n0 + nl];
            #pragma unroll
            for (int mt = 0; mt < 4; mt++) {
                ushortx4 pk;
                #pragma unroll
                for (int r = 0; r < 4; r++)
                    pk[r] = f2bf(silu_fast(acc[mt][nt][r] + bias));
                *(uintx2*)&lds.T[swz(nl, wm + mt * 16 + quad * 4)] = *(uintx2*)&pk;
            }
        }
        __syncthreads();
        const int b   = m0 >> 9;
        const int sg0 = m0 & (S_LEN - 1);
        const int eg0 = n0 - E_DIMC;
        #pragma unroll
        for (int i = 0; i < 8; i++) {
            int idx = tid + i * 256;
            int e   = idx >> 4;
            int j   = idx & 15;
            *(uintx4*)(vT + ((size_t)b * E_DIMC + eg0 + e) * S_LEN + sg0 + j * 8) =
                *(const uintx4*)&lds.T[swz(e, j * 8)];
        }
    } else {
        #pragma unroll
        for (int mt = 0; mt < 4; mt++)
            #pragma unroll
            for (int nt = 0; nt < 4; nt++)
                #pragma unroll
                for (int r = 0; r < 4; r++) {
                    int m = m0 + wm + mt * 16 + quad * 4 + r;
                    int n = n0 + wn + nt * 16 + l16;
                    float val = acc[mt][nt][r] + uvb[n];
                    base[(size_t)m * D_DIM + (n - 2 * E_DIMC)] = silu_fast(val);
                }
    }
}

// ---------------------------------------------------------------------------
// qk: P = relu((q k^T + w_bias)/sqrt(128))^2, SWAPPED, swizzled LDS transpose
// ---------------------------------------------------------------------------
__global__ __launch_bounds__(256) void gemm_qk_kernel(const unsigned short* __restrict__ q,
                                                      const unsigned short* __restrict__ k,
                                                      const float* __restrict__ wbias,
                                                      unsigned short* __restrict__ P) {
    __shared__ LdsU lds;
    floatx4 acc[4][4];
    size_t boff = (size_t)blockIdx.z * S_LEN * D_DIM;
    unsigned short* Pb = P + (size_t)blockIdx.z * S_LEN * S_LEN;
    const int m0 = blockIdx.x * 128, n0 = blockIdx.y * 128;
    gemm_bt_core<true>(q + boff, k + boff, D_DIM, D_DIM, D_DIM, m0, n0, lds.g, acc);

    const int tid = threadIdx.x, lane = tid & 63, wave = tid >> 6;
    const int quad = lane >> 4, l16 = lane & 15;
    const int wm = (wave >> 1) * 64, wn = (wave & 1) * 64;
    #pragma unroll
    for (int mt = 0; mt < 4; mt++) {
        int row = wm + mt * 16 + l16;
        int s   = m0 + row;
        #pragma unroll
        for (int nt = 0; nt < 4; nt++) {
            int nl = wn + nt * 16 + quad * 4;
            int t0 = n0 + nl;
            ushortx4 pk;
            #pragma unroll
            for (int r = 0; r < 4; r++) {
                float z = (acc[mt][nt][r] + wbias[t0 + r - s + (S_LEN - 1)]) * 0.08838834764831845f;
                z = fmaxf(z, 0.f);
                pk[r] = f2bf(z * z);
            }
            *(uintx2*)&lds.T[swz(row, nl)] = *(uintx2*)&pk;
        }
    }
    __syncthreads();
    #pragma unroll
    for (int i = 0; i < 8; i++) {
        int idx = tid + i * 256;
        int row = idx >> 4;
        int j   = idx & 15;
        *(uintx4*)(Pb + (size_t)(m0 + row) * S_LEN + n0 + j * 8) =
            *(const uintx4*)&lds.T[swz(row, j * 8)];
    }
}

// ---------------------------------------------------------------------------
// PV: u <- u .* (P @ v), SWAPPED; swizzled transpose; coalesced b128 update
// ---------------------------------------------------------------------------
__global__ __launch_bounds__(256) void gemm_pv_kernel(const unsigned short* __restrict__ P,
                                                      const unsigned short* __restrict__ vT,
                                                      unsigned short* __restrict__ u) {
    __shared__ LdsU lds;
    floatx4 acc[4][4];
    int bb = blockIdx.z;
    const unsigned short* Pb  = P  + (size_t)bb * S_LEN * S_LEN;
    const unsigned short* vTb = vT + (size_t)bb * E_DIMC * S_LEN;
    const int m0 = blockIdx.x * 128, n0 = blockIdx.y * 128;
    gemm_bt_core<true>(Pb, vTb, S_LEN, S_LEN, S_LEN, m0, n0, lds.g, acc);

    const int tid = threadIdx.x, lane = tid & 63, wave = tid >> 6;
    const int quad = lane >> 4, l16 = lane & 15;
    const int wm = (wave >> 1) * 64, wn = (wave & 1) * 64;
    #pragma unroll
    for (int mt = 0; mt < 4; mt++) {
        int row = wm + mt * 16 + l16;
        #pragma unroll
        for (int nt = 0; nt < 4; nt++) {
            int nl = wn + nt * 16 + quad * 4;
            ushortx4 pk;
            #pragma unroll
            for (int r = 0; r < 4; r++) pk[r] = f2bf(acc[mt][nt][r]);
            *(uintx2*)&lds.T[swz(row, nl)] = *(uintx2*)&pk;
        }
    }
    __syncthreads();
    #pragma unroll
    for (int i = 0; i < 8; i++) {
        int idx = tid + i * 256;
        int row = idx >> 4;
        int j   = idx & 15;
        size_t off = ((size_t)bb * S_LEN + m0 + row) * E_DIMC + n0 + j * 8;
        union { uintx4 u4; unsigned short s[8]; } tv, uv, ov;
        tv.u4 = *(const uintx4*)&lds.T[swz(row, j * 8)];
        uv.u4 = *(const uintx4*)(u + off);
        #pragma unroll
        for (int jj = 0; jj < 8; jj++) ov.s[jj] = f2bf(bf2f(tv.s[jj]) * bf2f(uv.s[jj]));
        *(uintx4*)(u + off) = ov.u4;
    }
}

// ---------------------------------------------------------------------------
// OUT: out = oe @ o_w^T + o_b + x, SWAPPED. acc floatx4 = 4 consecutive n ->
// DIRECT global float4 stores (no LDS, no barriers); coalesced x/o_b reads.
// ---------------------------------------------------------------------------
__global__ __launch_bounds__(256) void gemm_out_kernel(const unsigned short* __restrict__ oe,
                                                       const unsigned short* __restrict__ ow,
                                                       const float* __restrict__ ob,
                                                       const float* __restrict__ x,
                                                       float* __restrict__ out) {
    __shared__ GemmLds lds;
    floatx4 acc[4][4];
    const int m0 = blockIdx.x * 128, n0 = blockIdx.y * 128;
    gemm_bt_core<true>(oe, ow, E_DIMC, E_DIMC, E_DIMC, m0, n0, lds, acc);

    const int tid = threadIdx.x, lane = tid & 63, wave = tid >> 6;
    const int quad = lane >> 4, l16 = lane & 15;
    const int wm = (wave >> 1) * 64, wn = (wave & 1) * 64;

    #pragma unroll
    for (int mt = 0; mt < 4; mt++) {
        int m = m0 + wm + mt * 16 + l16;
        #pragma unroll
        for (int nt = 0; nt < 4; nt++) {
            int n = n0 + wn + nt * 16 + quad * 4;
            size_t off = (size_t)m * H_DIM + n;
            floatx4 b4 = *(const floatx4*)&ob[n];
            floatx4 x4 = *(const floatx4*)&x[off];
            *(floatx4*)&out[off] = acc[mt][nt] + b4 + x4;
        }
    }
}

// ---------------------------------------------------------------------------
extern "C" void kernel_launch(void* const* d_in, const int* in_sizes, int n_in,
                              void* d_out, int out_size, void* d_ws, size_t ws_size,
                              hipStream_t stream) {
    const float* x     = (const float*)d_in[0];
    const float* ln_g  = (const float*)d_in[1];
    const float* uv_w  = (const float*)d_in[2];
    const float* uv_b  = (const float*)d_in[3];
    const float* gamma = (const float*)d_in[4];
    const float* beta  = (const float*)d_in[5];
    const float* wbias = (const float*)d_in[6];
    const float* o_w   = (const float*)d_in[7];
    const float* o_b   = (const float*)d_in[8];
    float* out = (float*)d_out;

    char* ws = (char*)d_ws;
    size_t off = 0;
    auto alloc = [&](size_t bytes) {
        void* p = ws + off;
        off += (bytes + 255) & ~(size_t)255;
        return p;
    };
    // Peak ~196.4 MiB:
    unsigned short* u     = (unsigned short*)alloc((size_t)M_TOT * E_DIMC * 2);      // 64 MiB (u, then oe in place)
    unsigned short* vT    = (unsigned short*)alloc((size_t)64 * E_DIMC * S_LEN * 2); // 64 MiB
    unsigned short* xn    = (unsigned short*)alloc((size_t)M_TOT * H_DIM * 2);       // 32 MiB
    unsigned short* P     = xn;                                                      // alias (xn dead after gemm1)
    float*          base  = (float*)alloc((size_t)M_TOT * D_DIM * 4);                // 16 MiB
    unsigned short* q     = (unsigned short*)alloc((size_t)M_TOT * D_DIM * 2);       // 8 MiB
    unsigned short* k     = (unsigned short*)alloc((size_t)M_TOT * D_DIM * 2);       // 8 MiB
    float*          cost  = (float*)alloc((size_t)S_LEN * 64 * 4);
    float*          sint  = (float*)alloc((size_t)S_LEN * 64 * 4);
    unsigned short* uvwb  = (unsigned short*)alloc((size_t)UV_DIM * H_DIM * 2);      // 2.2 MiB
    unsigned short* owb   = (unsigned short*)alloc((size_t)H_DIM * E_DIMC * 2);      // 1 MiB
    (void)ws_size; (void)in_sizes; (void)n_in; (void)out_size;

    f2bf_kernel<<<(UV_DIM * H_DIM / 4 + 255) / 256, 256, 0, stream>>>(uv_w, uvwb, UV_DIM * H_DIM / 4);
    f2bf_kernel<<<(H_DIM * E_DIMC / 4 + 255) / 256, 256, 0, stream>>>(o_w, owb, H_DIM * E_DIMC / 4);
    rope_table_kernel<<<S_LEN, 64, 0, stream>>>(cost, sint);

    rmsnorm_kernel<<<M_TOT / 4, 256, 0, stream>>>(x, ln_g, xn);

    // gemm1 + silu: u (swapped) and v/base (unswapped)
    gemm1_u_kernel<<<dim3(M_TOT / 128, 8), 256, 0, stream>>>(xn, uvwb, uv_b, u);
    gemm1_vbase_kernel<<<dim3(M_TOT / 128, 9), 256, 0, stream>>>(xn, uvwb, uv_b, vT, base);

    rope_apply_kernel<<<M_TOT * 64 / 256, 256, 0, stream>>>(base, gamma, beta, cost, sint, q, k);

    // P = relu^2((q k^T + bias)/sqrt(128))   (overwrites xn region)
    gemm_qk_kernel<<<dim3(S_LEN / 128, S_LEN / 128, 64), 256, 0, stream>>>(q, k, wbias, P);

    // u <- u .* (P @ v)  in place
    gemm_pv_kernel<<<dim3(S_LEN / 128, E_DIMC / 128, 64), 256, 0, stream>>>(P, vT, u);

    // out = oe @ o_w^T + o_b + x
    gemm_out_kernel<<<dim3(M_TOT / 128, H_DIM / 128), 256, 0, stream>>>(u, owb, o_b, x, out);
}

// Round 7
// 399.381 us; speedup vs baseline: 1.0713x; 1.0257x over previous
//
#include <hip/hip_runtime.h>
#include <math.h>

// ---------------------------------------------------------------------------
// GAU-alpha fused block for MI355X (gfx950).
// B=64, S=512, H=512, E=1024, UV=2176, D=128, M=B*S=32768.
// bf16 MFMA (16x16x32) all matmuls; fp32 elsewhere.
// Round 7: re-merge gemm1 (r5 split cost ~25us: double xn stream + launch);
// keep r6 conflict-free epilogues. gemm_out grid n-fastest for oe L2 reuse.
// ---------------------------------------------------------------------------

#define M_TOT   32768
#define S_LEN   512
#define H_DIM   512
#define E_DIMC  1024
#define UV_DIM  2176
#define D_DIM   128

using floatx4  = __attribute__((ext_vector_type(4))) float;
using uintx2   = __attribute__((ext_vector_type(2))) unsigned int;
using uintx4   = __attribute__((ext_vector_type(4))) unsigned int;
using ushortx4 = __attribute__((ext_vector_type(4))) unsigned short;
using short8   = __attribute__((ext_vector_type(8))) short;

#define ASYNC_CP16(gsrc, ldst)                                                  \
    __builtin_amdgcn_global_load_lds(                                           \
        (const __attribute__((address_space(1))) void*)(gsrc),                  \
        (__attribute__((address_space(3))) void*)(ldst), 16, 0, 0)

__device__ __forceinline__ float bf2f(unsigned short h) {
    union { unsigned int u; float f; } c;
    c.u = ((unsigned int)h) << 16;
    return c.f;
}
__device__ __forceinline__ unsigned short f2bf(float f) {
    union { float f; unsigned int u; } c;
    c.f = f;
    unsigned int r = c.u + 0x7fffu + ((c.u >> 16) & 1u);  // RNE
    return (unsigned short)(r >> 16);
}
__device__ __forceinline__ float silu_fast(float x) {
    float e = __expf(-x);                       // v_exp_f32
    return x * __builtin_amdgcn_rcpf(1.0f + e); // v_rcp_f32
}

// ---------------------------------------------------------------------------
__global__ __launch_bounds__(256) void f2bf_kernel(const float* __restrict__ in,
                                                   unsigned short* __restrict__ out,
                                                   int n4) {
    int i = blockIdx.x * 256 + threadIdx.x;
    if (i < n4) {
        floatx4 v = ((const floatx4*)in)[i];
        ushortx4 o;
        o.x = f2bf(v.x); o.y = f2bf(v.y); o.z = f2bf(v.z); o.w = f2bf(v.w);
        ((ushortx4*)out)[i] = o;
    }
}

// ---------------------------------------------------------------------------
__global__ __launch_bounds__(256) void rmsnorm_kernel(const float* __restrict__ x,
                                                      const float* __restrict__ ln_g,
                                                      unsigned short* __restrict__ xn) {
    int row  = blockIdx.x * 4 + (threadIdx.x >> 6);
    int lane = threadIdx.x & 63;
    const float* xr = x + (size_t)row * H_DIM;
    floatx4 v0 = ((const floatx4*)xr)[lane];
    floatx4 v1 = ((const floatx4*)xr)[lane + 64];
    float ss = v0.x*v0.x + v0.y*v0.y + v0.z*v0.z + v0.w*v0.w
             + v1.x*v1.x + v1.y*v1.y + v1.z*v1.z + v1.w*v1.w;
    #pragma unroll
    for (int off = 32; off > 0; off >>= 1) ss += __shfl_xor(ss, off, 64);
    float norm = sqrtf(ss) * 0.044194173824159216f;  // * H^-0.5
    float sc   = ln_g[0] / fmaxf(norm, 1e-5f);
    unsigned short* xo = xn + (size_t)row * H_DIM;
    ushortx4 o0, o1;
    o0.x = f2bf(v0.x * sc); o0.y = f2bf(v0.y * sc);
    o0.z = f2bf(v0.z * sc); o0.w = f2bf(v0.w * sc);
    o1.x = f2bf(v1.x * sc); o1.y = f2bf(v1.y * sc);
    o1.z = f2bf(v1.z * sc); o1.w = f2bf(v1.w * sc);
    ((ushortx4*)xo)[lane]      = o0;
    ((ushortx4*)xo)[lane + 64] = o1;
}

// ---------------------------------------------------------------------------
__global__ __launch_bounds__(64) void rope_table_kernel(float* __restrict__ cost,
                                                        float* __restrict__ sint) {
    int s = blockIdx.x;
    int j = threadIdx.x;  // 0..63
    float invf = (float)pow(10000.0, (double)j / 64.0);
    float ang  = (float)s * invf;  // fp32 multiply like the f32 reference
    double a   = (double)ang;
    cost[s * 64 + j] = (float)cos(a);
    sint[s * 64 + j] = (float)sin(a);
}

// ---------------------------------------------------------------------------
__global__ __launch_bounds__(256) void rope_apply_kernel(const float* __restrict__ base,
                                                         const float* __restrict__ gamma,
                                                         const float* __restrict__ beta,
                                                         const float* __restrict__ cost,
                                                         const float* __restrict__ sint,
                                                         unsigned short* __restrict__ q,
                                                         unsigned short* __restrict__ k) {
    int idx = blockIdx.x * 256 + threadIdx.x;  // M*64 total
    int m = idx >> 6;
    int j = idx & 63;
    int s = m & (S_LEN - 1);
    float b1 = base[(size_t)m * D_DIM + j];
    float b2 = base[(size_t)m * D_DIM + 64 + j];
    float c  = cost[s * 64 + j];
    float sn = sint[s * 64 + j];
    float yq1 = b1 * gamma[j]       + beta[j];
    float yq2 = b2 * gamma[64 + j]  + beta[64 + j];
    float yk1 = b1 * gamma[128 + j] + beta[128 + j];
    float yk2 = b2 * gamma[192 + j] + beta[192 + j];
    q[(size_t)m * D_DIM + j]      = f2bf(yq1 * c - yq2 * sn);
    q[(size_t)m * D_DIM + 64 + j] = f2bf(yq2 * c + yq1 * sn);
    k[(size_t)m * D_DIM + j]      = f2bf(yk1 * c - yk2 * sn);
    k[(size_t)m * D_DIM + 64 + j] = f2bf(yk2 * c + yk1 * sn);
}

// ---------------------------------------------------------------------------
// GEMM core, B^T form: C[m][n] = sum_k A[m][k]*B[n][k].
// 128x128 tile, 4 waves (64x64 each), 16x16x32 bf16 MFMA, BK=64.
// Staging: global_load_lds w=16, XOR-swizzled: LDS[r][c] = G[r][c ^ 8*(r&7)].
// SWAPT=false: acc C-layout: m = wm+mt*16+quad*4+r, n = wn+nt*16+l16
// SWAPT=true : C^T:           m = wm+mt*16+l16,     n = wn+nt*16+quad*4+r
// ---------------------------------------------------------------------------
struct GemmLds {
    unsigned short As[128 * 64];
    unsigned short Bs[128 * 64];
};

template <bool SWAPT>
__device__ __forceinline__ void gemm_bt_core(const unsigned short* __restrict__ A,
                                             const unsigned short* __restrict__ B,
                                             int lda, int ldb, int K,
                                             int m0, int n0,
                                             GemmLds& lds, floatx4 (&acc)[4][4]) {
    const int tid  = threadIdx.x;
    const int lane = tid & 63;
    const int wave = tid >> 6;
    const int quad = lane >> 4;
    const int l16  = lane & 15;
    const int wm   = (wave >> 1) * 64;
    const int wn   = (wave & 1) * 64;
    const int lrow = lane >> 3;                    // 0..7
    const int cgs  = ((lane & 7) ^ lrow) * 8;      // swizzled source col (shorts)

    #pragma unroll
    for (int i = 0; i < 4; i++)
        #pragma unroll
        for (int j = 0; j < 4; j++) acc[i][j] = (floatx4){0.f, 0.f, 0.f, 0.f};

    for (int kt = 0; kt < K; kt += 64) {
        #pragma unroll
        for (int i = 0; i < 4; i++) {
            int r0 = wave * 32 + i * 8;
            const unsigned short* ga = A + (size_t)(m0 + r0 + lrow) * lda + kt + cgs;
            const unsigned short* gb = B + (size_t)(n0 + r0 + lrow) * ldb + kt + cgs;
            ASYNC_CP16(ga, &lds.As[r0 * 64]);
            ASYNC_CP16(gb, &lds.Bs[r0 * 64]);
        }
        __syncthreads();
        #pragma unroll
        for (int kk = 0; kk < 64; kk += 32) {
            short8 af[4], bf[4];
            const int pc = (kk + quad * 8) ^ ((l16 & 7) * 8);  // physical col
            #pragma unroll
            for (int mt = 0; mt < 4; mt++) {
                int row = wm + mt * 16 + l16;
                union { short8 s8; uintx4 u4; } fu;
                fu.u4 = *(const uintx4*)&lds.As[row * 64 + pc];
                af[mt] = fu.s8;
            }
            #pragma unroll
            for (int nt = 0; nt < 4; nt++) {
                int row = wn + nt * 16 + l16;
                union { short8 s8; uintx4 u4; } fu;
                fu.u4 = *(const uintx4*)&lds.Bs[row * 64 + pc];
                bf[nt] = fu.s8;
            }
            #pragma unroll
            for (int mt = 0; mt < 4; mt++)
                #pragma unroll
                for (int nt = 0; nt < 4; nt++)
                    acc[mt][nt] = SWAPT
                        ? __builtin_amdgcn_mfma_f32_16x16x32_bf16(bf[nt], af[mt], acc[mt][nt], 0, 0, 0)
                        : __builtin_amdgcn_mfma_f32_16x16x32_bf16(af[mt], bf[nt], acc[mt][nt], 0, 0, 0);
        }
        __syncthreads();
    }
}

// bf16 epilogue tile: pitch 128 shorts, 16B-granular XOR swizzle:
//   phys 8B-chunk: col -> ((col>>3) ^ (row&7))*8 + (col&7)
// b64 writes 2-way (free), b128 reads conflict-free.
union LdsU {
    GemmLds g;
    unsigned short T[128 * 128];   // 32768 B == sizeof(GemmLds)
};
__device__ __forceinline__ int swz(int row, int col) {
    return row * 128 + ((((col >> 3) ^ (row & 7)) << 3) | (col & 7));
}

// ---------------------------------------------------------------------------
// GEMM1 (merged): act = silu(xn @ uv_w^T + uv_b), grid (M/128, 17)
//   y <  8 : u columns, SWAPPED core, swizzled LDS transpose, b128 stores
//   y 8..15: v columns, UNSWAPPED, T[n][m] transpose -> vT (b,e,s)
//   y == 16: base columns, UNSWAPPED, fp32 scalar stores
// ---------------------------------------------------------------------------
__global__ __launch_bounds__(256) void gemm1_kernel(const unsigned short* __restrict__ xn,
                                                    const unsigned short* __restrict__ uvw,
                                                    const float* __restrict__ uvb,
                                                    unsigned short* __restrict__ u,
                                                    unsigned short* __restrict__ vT,
                                                    float* __restrict__ base) {
    __shared__ LdsU lds;
    floatx4 acc[4][4];
    const int m0 = blockIdx.x * 128, n0 = blockIdx.y * 128;

    const int tid = threadIdx.x, lane = tid & 63, wave = tid >> 6;
    const int quad = lane >> 4, l16 = lane & 15;
    const int wm = (wave >> 1) * 64, wn = (wave & 1) * 64;

    if (blockIdx.y < 8) {
        gemm_bt_core<true>(xn, uvw, H_DIM, H_DIM, H_DIM, m0, n0, lds.g, acc);
        #pragma unroll
        for (int mt = 0; mt < 4; mt++) {
            int row = wm + mt * 16 + l16;
            #pragma unroll
            for (int nt = 0; nt < 4; nt++) {
                int nl = wn + nt * 16 + quad * 4;
                floatx4 b4 = *(const floatx4*)&uvb[n0 + nl];
                ushortx4 pk;
                #pragma unroll
                for (int r = 0; r < 4; r++)
                    pk[r] = f2bf(silu_fast(acc[mt][nt][r] + b4[r]));
                *(uintx2*)&lds.T[swz(row, nl)] = *(uintx2*)&pk;
            }
        }
        __syncthreads();
        #pragma unroll
        for (int i = 0; i < 8; i++) {
            int idx = tid + i * 256;       // 0..2047
            int row = idx >> 4;            // 0..127
            int j   = idx & 15;
            *(uintx4*)(u + (size_t)(m0 + row) * E_DIMC + n0 + j * 8) =
                *(const uintx4*)&lds.T[swz(row, j * 8)];
        }
    } else if (blockIdx.y < 16) {
        gemm_bt_core<false>(xn, uvw, H_DIM, H_DIM, H_DIM, m0, n0, lds.g, acc);
        // v: T[n][m] (pack along m = quad*4+r), swizzled; then store vT (b,e,s)
        #pragma unroll
        for (int nt = 0; nt < 4; nt++) {
            int nl = wn + nt * 16 + l16;
            float bias = uvb[n0 + nl];
            #pragma unroll
            for (int mt = 0; mt < 4; mt++) {
                ushortx4 pk;
                #pragma unroll
                for (int r = 0; r < 4; r++)
                    pk[r] = f2bf(silu_fast(acc[mt][nt][r] + bias));
                *(uintx2*)&lds.T[swz(nl, wm + mt * 16 + quad * 4)] = *(uintx2*)&pk;
            }
        }
        __syncthreads();
        const int b   = m0 >> 9;
        const int sg0 = m0 & (S_LEN - 1);
        const int eg0 = n0 - E_DIMC;
        #pragma unroll
        for (int i = 0; i < 8; i++) {
            int idx = tid + i * 256;
            int e   = idx >> 4;
            int j   = idx & 15;
            *(uintx4*)(vT + ((size_t)b * E_DIMC + eg0 + e) * S_LEN + sg0 + j * 8) =
                *(const uintx4*)&lds.T[swz(e, j * 8)];
        }
    } else {
        gemm_bt_core<false>(xn, uvw, H_DIM, H_DIM, H_DIM, m0, n0, lds.g, acc);
        #pragma unroll
        for (int mt = 0; mt < 4; mt++)
            #pragma unroll
            for (int nt = 0; nt < 4; nt++)
                #pragma unroll
                for (int r = 0; r < 4; r++) {
                    int m = m0 + wm + mt * 16 + quad * 4 + r;
                    int n = n0 + wn + nt * 16 + l16;
                    float val = acc[mt][nt][r] + uvb[n];
                    base[(size_t)m * D_DIM + (n - 2 * E_DIMC)] = silu_fast(val);
                }
    }
}

// ---------------------------------------------------------------------------
// qk: P = relu((q k^T + w_bias)/sqrt(128))^2, SWAPPED, swizzled LDS transpose
// ---------------------------------------------------------------------------
__global__ __launch_bounds__(256) void gemm_qk_kernel(const unsigned short* __restrict__ q,
                                                      const unsigned short* __restrict__ k,
                                                      const float* __restrict__ wbias,
                                                      unsigned short* __restrict__ P) {
    __shared__ LdsU lds;
    floatx4 acc[4][4];
    size_t boff = (size_t)blockIdx.z * S_LEN * D_DIM;
    unsigned short* Pb = P + (size_t)blockIdx.z * S_LEN * S_LEN;
    const int m0 = blockIdx.x * 128, n0 = blockIdx.y * 128;
    gemm_bt_core<true>(q + boff, k + boff, D_DIM, D_DIM, D_DIM, m0, n0, lds.g, acc);

    const int tid = threadIdx.x, lane = tid & 63, wave = tid >> 6;
    const int quad = lane >> 4, l16 = lane & 15;
    const int wm = (wave >> 1) * 64, wn = (wave & 1) * 64;
    #pragma unroll
    for (int mt = 0; mt < 4; mt++) {
        int row = wm + mt * 16 + l16;
        int s   = m0 + row;
        #pragma unroll
        for (int nt = 0; nt < 4; nt++) {
            int nl = wn + nt * 16 + quad * 4;
            int t0 = n0 + nl;
            ushortx4 pk;
            #pragma unroll
            for (int r = 0; r < 4; r++) {
                float z = (acc[mt][nt][r] + wbias[t0 + r - s + (S_LEN - 1)]) * 0.08838834764831845f;
                z = fmaxf(z, 0.f);
                pk[r] = f2bf(z * z);
            }
            *(uintx2*)&lds.T[swz(row, nl)] = *(uintx2*)&pk;
        }
    }
    __syncthreads();
    #pragma unroll
    for (int i = 0; i < 8; i++) {
        int idx = tid + i * 256;
        int row = idx >> 4;
        int j   = idx & 15;
        *(uintx4*)(Pb + (size_t)(m0 + row) * S_LEN + n0 + j * 8) =
            *(const uintx4*)&lds.T[swz(row, j * 8)];
    }
}

// ---------------------------------------------------------------------------
// PV: u <- u .* (P @ v), SWAPPED; swizzled transpose; coalesced b128 update
// ---------------------------------------------------------------------------
__global__ __launch_bounds__(256) void gemm_pv_kernel(const unsigned short* __restrict__ P,
                                                      const unsigned short* __restrict__ vT,
                                                      unsigned short* __restrict__ u) {
    __shared__ LdsU lds;
    floatx4 acc[4][4];
    int bb = blockIdx.z;
    const unsigned short* Pb  = P  + (size_t)bb * S_LEN * S_LEN;
    const unsigned short* vTb = vT + (size_t)bb * E_DIMC * S_LEN;
    const int m0 = blockIdx.x * 128, n0 = blockIdx.y * 128;
    gemm_bt_core<true>(Pb, vTb, S_LEN, S_LEN, S_LEN, m0, n0, lds.g, acc);

    const int tid = threadIdx.x, lane = tid & 63, wave = tid >> 6;
    const int quad = lane >> 4, l16 = lane & 15;
    const int wm = (wave >> 1) * 64, wn = (wave & 1) * 64;
    #pragma unroll
    for (int mt = 0; mt < 4; mt++) {
        int row = wm + mt * 16 + l16;
        #pragma unroll
        for (int nt = 0; nt < 4; nt++) {
            int nl = wn + nt * 16 + quad * 4;
            ushortx4 pk;
            #pragma unroll
            for (int r = 0; r < 4; r++) pk[r] = f2bf(acc[mt][nt][r]);
            *(uintx2*)&lds.T[swz(row, nl)] = *(uintx2*)&pk;
        }
    }
    __syncthreads();
    #pragma unroll
    for (int i = 0; i < 8; i++) {
        int idx = tid + i * 256;
        int row = idx >> 4;
        int j   = idx & 15;
        size_t off = ((size_t)bb * S_LEN + m0 + row) * E_DIMC + n0 + j * 8;
        union { uintx4 u4; unsigned short s[8]; } tv, uv, ov;
        tv.u4 = *(const uintx4*)&lds.T[swz(row, j * 8)];
        uv.u4 = *(const uintx4*)(u + off);
        #pragma unroll
        for (int jj = 0; jj < 8; jj++) ov.s[jj] = f2bf(bf2f(tv.s[jj]) * bf2f(uv.s[jj]));
        *(uintx4*)(u + off) = ov.u4;
    }
}

// ---------------------------------------------------------------------------
// OUT: out = oe @ o_w^T + o_b + x, SWAPPED, direct float4 stores.
// grid = (N/128, M/128): n-tiles fastest so 4 blocks sharing an m-tile are
// dispatch-adjacent (oe A-tile L2 locality).
// ---------------------------------------------------------------------------
__global__ __launch_bounds__(256) void gemm_out_kernel(const unsigned short* __restrict__ oe,
                                                       const unsigned short* __restrict__ ow,
                                                       const float* __restrict__ ob,
                                                       const float* __restrict__ x,
                                                       float* __restrict__ out) {
    __shared__ GemmLds lds;
    floatx4 acc[4][4];
    const int m0 = blockIdx.y * 128, n0 = blockIdx.x * 128;
    gemm_bt_core<true>(oe, ow, E_DIMC, E_DIMC, E_DIMC, m0, n0, lds, acc);

    const int tid = threadIdx.x, lane = tid & 63, wave = tid >> 6;
    const int quad = lane >> 4, l16 = lane & 15;
    const int wm = (wave >> 1) * 64, wn = (wave & 1) * 64;

    #pragma unroll
    for (int mt = 0; mt < 4; mt++) {
        int m = m0 + wm + mt * 16 + l16;
        #pragma unroll
        for (int nt = 0; nt < 4; nt++) {
            int n = n0 + wn + nt * 16 + quad * 4;
            size_t off = (size_t)m * H_DIM + n;
            floatx4 b4 = *(const floatx4*)&ob[n];
            floatx4 x4 = *(const floatx4*)&x[off];
            *(floatx4*)&out[off] = acc[mt][nt] + b4 + x4;
        }
    }
}

// ---------------------------------------------------------------------------
extern "C" void kernel_launch(void* const* d_in, const int* in_sizes, int n_in,
                              void* d_out, int out_size, void* d_ws, size_t ws_size,
                              hipStream_t stream) {
    const float* x     = (const float*)d_in[0];
    const float* ln_g  = (const float*)d_in[1];
    const float* uv_w  = (const float*)d_in[2];
    const float* uv_b  = (const float*)d_in[3];
    const float* gamma = (const float*)d_in[4];
    const float* beta  = (const float*)d_in[5];
    const float* wbias = (const float*)d_in[6];
    const float* o_w   = (const float*)d_in[7];
    const float* o_b   = (const float*)d_in[8];
    float* out = (float*)d_out;

    char* ws = (char*)d_ws;
    size_t off = 0;
    auto alloc = [&](size_t bytes) {
        void* p = ws + off;
        off += (bytes + 255) & ~(size_t)255;
        return p;
    };
    // Peak ~196.4 MiB:
    unsigned short* u     = (unsigned short*)alloc((size_t)M_TOT * E_DIMC * 2);      // 64 MiB (u, then oe in place)
    unsigned short* vT    = (unsigned short*)alloc((size_t)64 * E_DIMC * S_LEN * 2); // 64 MiB
    unsigned short* xn    = (unsigned short*)alloc((size_t)M_TOT * H_DIM * 2);       // 32 MiB
    unsigned short* P     = xn;                                                      // alias (xn dead after gemm1)
    float*          base  = (float*)alloc((size_t)M_TOT * D_DIM * 4);                // 16 MiB
    unsigned short* q     = (unsigned short*)alloc((size_t)M_TOT * D_DIM * 2);       // 8 MiB
    unsigned short* k     = (unsigned short*)alloc((size_t)M_TOT * D_DIM * 2);       // 8 MiB
    float*          cost  = (float*)alloc((size_t)S_LEN * 64 * 4);
    float*          sint  = (float*)alloc((size_t)S_LEN * 64 * 4);
    unsigned short* uvwb  = (unsigned short*)alloc((size_t)UV_DIM * H_DIM * 2);      // 2.2 MiB
    unsigned short* owb   = (unsigned short*)alloc((size_t)H_DIM * E_DIMC * 2);      // 1 MiB
    (void)ws_size; (void)in_sizes; (void)n_in; (void)out_size;

    f2bf_kernel<<<(UV_DIM * H_DIM / 4 + 255) / 256, 256, 0, stream>>>(uv_w, uvwb, UV_DIM * H_DIM / 4);
    f2bf_kernel<<<(H_DIM * E_DIMC / 4 + 255) / 256, 256, 0, stream>>>(o_w, owb, H_DIM * E_DIMC / 4);
    rope_table_kernel<<<S_LEN, 64, 0, stream>>>(cost, sint);

    rmsnorm_kernel<<<M_TOT / 4, 256, 0, stream>>>(x, ln_g, xn);

    // gemm1 + silu (merged): u / vT / base
    gemm1_kernel<<<dim3(M_TOT / 128, 17), 256, 0, stream>>>(xn, uvwb, uv_b, u, vT, base);

    rope_apply_kernel<<<M_TOT * 64 / 256, 256, 0, stream>>>(base, gamma, beta, cost, sint, q, k);

    // P = relu^2((q k^T + bias)/sqrt(128))   (overwrites xn region)
    gemm_qk_kernel<<<dim3(S_LEN / 128, S_LEN / 128, 64), 256, 0, stream>>>(q, k, wbias, P);

    // u <- u .* (P @ v)  in place
    gemm_pv_kernel<<<dim3(S_LEN / 128, E_DIMC / 128, 64), 256, 0, stream>>>(P, vT, u);

    // out = oe @ o_w^T + o_b + x
    gemm_out_kernel<<<dim3(H_DIM / 128, M_TOT / 128), 256, 0, stream>>>(u, owb, o_b, x, out);
}